// Round 7
// baseline (1200.349 us; speedup 1.0000x reference)
//
#include <hip/hip_runtime.h>
#include <hip/hip_fp16.h>
#include <math.h>

#define F_IN 128
#define HID 64
#define HID2 32
#define EPS_BN 1e-5f
#define BW 128          // nodes per bucket
#define NBMAX 1024      // padded bucket count (actual NB = 782)
#define CAP 2560        // max edges per bucket (mean ~2046, +11 sigma)
#define CH 8192         // edges per partition workgroup

// ---------------- phase A: chunk counting-sort into bucket regions (1024 thr) ----------------
__global__ __launch_bounds__(1024) void partition_kernel(const int* __restrict__ src, const int* __restrict__ dst,
                                                         int E, int* __restrict__ gcursor,
                                                         unsigned* __restrict__ ebuf) {
    __shared__ int hist[NBMAX];   // 4 KB each
    __shared__ int start[NBMAX];
    __shared__ int cur[NBMAX];
    __shared__ int gb[NBMAX];
    __shared__ int sc[1024];
    __shared__ unsigned buf[CH];  // 32 KB
    int tid = threadIdx.x;
    int e0 = blockIdx.x * CH;
    hist[tid] = 0;
    __syncthreads();
#pragma unroll
    for (int it = 0; it < CH / 1024; it++) {
        int e = e0 + tid + it * 1024;
        if (e < E) atomicAdd(&hist[dst[e] >> 7], 1);
    }
    __syncthreads();
    int v = hist[tid];
    sc[tid] = v;
    __syncthreads();
    for (int off = 1; off < 1024; off <<= 1) {
        int t = (tid >= off) ? sc[tid - off] : 0;
        __syncthreads();
        sc[tid] += t;
        __syncthreads();
    }
    int ex = sc[tid] - v;  // exclusive prefix over buckets
    start[tid] = ex;
    cur[tid] = ex;
    gb[tid] = v ? atomicAdd(&gcursor[tid], v) : 0;   // reserve run in bucket region
    __syncthreads();
#pragma unroll
    for (int it = 0; it < CH / 1024; it++) {
        int e = e0 + tid + it * 1024;
        if (e < E) {
            int d = dst[e], s = src[e];
            int p = atomicAdd(&cur[d >> 7], 1);
            buf[p] = ((unsigned)(d & (BW - 1)) << 17) | (unsigned)s;  // src < 2^17
        }
    }
    __syncthreads();
    // write phase: 256 quad-groups x 4 buckets each
    int grp = tid >> 2, sub = tid & 3;
    for (int b = grp; b < NBMAX; b += 256) {
        int len = hist[b];
        if (!len) continue;
        int st = start[b];
        unsigned* dp = ebuf + (size_t)b * CAP + gb[b];
        for (int i = sub; i < len; i += 4) dp[i] = buf[st + i];
    }
}

// ---------------- degrees + dinv (per bucket LDS histogram) ----------------
__global__ __launch_bounds__(256) void degree_kernel(const unsigned* __restrict__ ebuf, const int* __restrict__ gcursor,
                                                     float* __restrict__ dinv, int n) {
    __shared__ int ldeg[BW];
    int b = blockIdx.x, tid = threadIdx.x;
    int base = b * CAP, len = gcursor[b];
    int node0 = b * BW;
    int nn = min(BW, n - node0);
    if (tid < BW) ldeg[tid] = 0;
    __syncthreads();
    for (int k = tid; k < len; k += 256) atomicAdd(&ldeg[ebuf[base + k] >> 17], 1);
    __syncthreads();
    if (tid < nn) dinv[node0 + tid] = rsqrtf((float)(ldeg[tid] + 1));   // +1 self-loop
}

// ---------------- fold BN(eval)+bias into per-column scale/shift ----------------
__global__ void constprep_kernel(const float* g1, const float* be1, const float* rm1, const float* rv1, const float* b1,
                                 const float* g2, const float* be2, const float* rm2, const float* rv2, const float* b2,
                                 float* A1, float* B1, float* A2, float* B2) {
    int t = threadIdx.x;
    if (t < HID)  { float s = g1[t] * rsqrtf(rv1[t] + EPS_BN); A1[t] = s; B1[t] = (b1[t] - rm1[t]) * s + be1[t]; }
    if (t < HID2) { float s = g2[t] * rsqrtf(rv2[t] + EPS_BN); A2[t] = s; B2[t] = (b2[t] - rm2[t]) * s + be2[t]; }
}

// ---------------- GEMM1: ht1 = fp16( (x @ W1) * dinv[row] ) ----------------
#define XP1 132
__global__ __launch_bounds__(256) void gemm1_kernel(const float* __restrict__ x, const float* __restrict__ W1,
                                                    const float* __restrict__ dinv, __half* __restrict__ ht1,
                                                    int n) {
    __shared__ float wlds[F_IN * HID];   // 32 KB, [k][col]
    __shared__ float xlds[64 * XP1];     // 33.8 KB
    int tid = threadIdx.x;
    {
        const float4* wv = (const float4*)W1;
        float4* wl = (float4*)wlds;
#pragma unroll
        for (int i = 0; i < F_IN * HID / 4 / 256; i++) wl[tid + 256 * i] = wv[tid + 256 * i];
    }
    int row0 = blockIdx.x * 64;
    {
        const float4* xv = (const float4*)(x + (size_t)row0 * F_IN);
        int lim = (n - row0) * (F_IN / 4);
#pragma unroll
        for (int i = 0; i < 8; i++) {
            int f = tid + 256 * i;
            float4 v = make_float4(0.f, 0.f, 0.f, 0.f);
            if (f < lim) v = xv[f];
            int r = f >> 5, kp = (f & 31) * 4;
            *(float4*)&xlds[r * XP1 + kp] = v;
        }
    }
    __syncthreads();
    int col4 = (tid & 15) * 4;
    int rowg = tid >> 4;
    float acc[4][4];
#pragma unroll
    for (int r = 0; r < 4; r++)
#pragma unroll
        for (int c = 0; c < 4; c++) acc[r][c] = 0.f;
#pragma unroll 4
    for (int k = 0; k < F_IN; k += 4) {
        float4 wb[4];
#pragma unroll
        for (int j = 0; j < 4; j++) wb[j] = *(const float4*)&wlds[(k + j) * HID + col4];
#pragma unroll
        for (int r = 0; r < 4; r++) {
            float4 xa = *(const float4*)&xlds[(rowg * 4 + r) * XP1 + k];
            acc[r][0] = fmaf(xa.x, wb[0].x, acc[r][0]); acc[r][1] = fmaf(xa.x, wb[0].y, acc[r][1]);
            acc[r][2] = fmaf(xa.x, wb[0].z, acc[r][2]); acc[r][3] = fmaf(xa.x, wb[0].w, acc[r][3]);
            acc[r][0] = fmaf(xa.y, wb[1].x, acc[r][0]); acc[r][1] = fmaf(xa.y, wb[1].y, acc[r][1]);
            acc[r][2] = fmaf(xa.y, wb[1].z, acc[r][2]); acc[r][3] = fmaf(xa.y, wb[1].w, acc[r][3]);
            acc[r][0] = fmaf(xa.z, wb[2].x, acc[r][0]); acc[r][1] = fmaf(xa.z, wb[2].y, acc[r][1]);
            acc[r][2] = fmaf(xa.z, wb[2].z, acc[r][2]); acc[r][3] = fmaf(xa.z, wb[2].w, acc[r][3]);
            acc[r][0] = fmaf(xa.w, wb[3].x, acc[r][0]); acc[r][1] = fmaf(xa.w, wb[3].y, acc[r][1]);
            acc[r][2] = fmaf(xa.w, wb[3].z, acc[r][2]); acc[r][3] = fmaf(xa.w, wb[3].w, acc[r][3]);
        }
    }
    int rbase = row0 + rowg * 4;
#pragma unroll
    for (int r = 0; r < 4; r++) {
        int row = rbase + r;
        if (row < n) {
            float d = dinv[row];
            __half2 h0, h1;
            h0.x = __float2half(acc[r][0] * d); h0.y = __float2half(acc[r][1] * d);
            h1.x = __float2half(acc[r][2] * d); h1.y = __float2half(acc[r][3] * d);
            __half2* dp = (__half2*)(ht1 + (size_t)row * HID + col4);
            dp[0] = h0; dp[1] = h1;
        }
    }
}

// ---------------- GEMM2: ht2 = fp16( (h1p @ W2) * dinv[row] ) ----------------
#define XP2 68
__global__ __launch_bounds__(256) void gemm2_kernel(const float* __restrict__ h1p, const float* __restrict__ W2,
                                                    const float* __restrict__ dinv, __half* __restrict__ ht2,
                                                    int n) {
    __shared__ float wlds[HID * HID2];   // 8 KB, [k][col]
    __shared__ float xlds[64 * XP2];     // 17.4 KB
    int tid = threadIdx.x;
    {
        const float4* wv = (const float4*)W2;
        float4* wl = (float4*)wlds;
#pragma unroll
        for (int i = 0; i < HID * HID2 / 4 / 256; i++) wl[tid + 256 * i] = wv[tid + 256 * i];
    }
    int row0 = blockIdx.x * 64;
    {
        const float4* xv = (const float4*)(h1p + (size_t)row0 * HID);
        int lim = (n - row0) * (HID / 4);
#pragma unroll
        for (int i = 0; i < 4; i++) {
            int f = tid + 256 * i;
            float4 v = make_float4(0.f, 0.f, 0.f, 0.f);
            if (f < lim) v = xv[f];
            int r = f >> 4, kp = (f & 15) * 4;
            *(float4*)&xlds[r * XP2 + kp] = v;
        }
    }
    __syncthreads();
    int col4 = (tid & 7) * 4;
    int rowg = tid >> 3;
    float acc[2][4];
#pragma unroll
    for (int r = 0; r < 2; r++)
#pragma unroll
        for (int c = 0; c < 4; c++) acc[r][c] = 0.f;
#pragma unroll 4
    for (int k = 0; k < HID; k += 4) {
        float4 wb[4];
#pragma unroll
        for (int j = 0; j < 4; j++) wb[j] = *(const float4*)&wlds[(k + j) * HID2 + col4];
#pragma unroll
        for (int r = 0; r < 2; r++) {
            float4 xa = *(const float4*)&xlds[(rowg * 2 + r) * XP2 + k];
            acc[r][0] = fmaf(xa.x, wb[0].x, acc[r][0]); acc[r][1] = fmaf(xa.x, wb[0].y, acc[r][1]);
            acc[r][2] = fmaf(xa.x, wb[0].z, acc[r][2]); acc[r][3] = fmaf(xa.x, wb[0].w, acc[r][3]);
            acc[r][0] = fmaf(xa.y, wb[1].x, acc[r][0]); acc[r][1] = fmaf(xa.y, wb[1].y, acc[r][1]);
            acc[r][2] = fmaf(xa.y, wb[1].z, acc[r][2]); acc[r][3] = fmaf(xa.y, wb[1].w, acc[r][3]);
            acc[r][0] = fmaf(xa.z, wb[2].x, acc[r][0]); acc[r][1] = fmaf(xa.z, wb[2].y, acc[r][1]);
            acc[r][2] = fmaf(xa.z, wb[2].z, acc[r][2]); acc[r][3] = fmaf(xa.z, wb[2].w, acc[r][3]);
            acc[r][0] = fmaf(xa.w, wb[3].x, acc[r][0]); acc[r][1] = fmaf(xa.w, wb[3].y, acc[r][1]);
            acc[r][2] = fmaf(xa.w, wb[3].z, acc[r][2]); acc[r][3] = fmaf(xa.w, wb[3].w, acc[r][3]);
        }
    }
    int rbase = row0 + rowg * 2;
#pragma unroll
    for (int r = 0; r < 2; r++) {
        int row = rbase + r;
        if (row < n) {
            float d = dinv[row];
            __half2 h0, h1;
            h0.x = __float2half(acc[r][0] * d); h0.y = __float2half(acc[r][1] * d);
            h1.x = __float2half(acc[r][2] * d); h1.y = __float2half(acc[r][3] * d);
            __half2* dp = (__half2*)(ht2 + (size_t)row * HID2 + col4);
            dp[0] = h0; dp[1] = h1;
        }
    }
}

// ---------------- agg1 (edge-parallel, LDS accumulate): h1p = relu(BN(dinv*(self + sum))) ----------------
#define FS1 65   // facc row stride (floats)
__global__ __launch_bounds__(256) void agg1_kernel(const __half* __restrict__ ht1, const unsigned* __restrict__ ebuf,
                                                   const int* __restrict__ gcursor, const float* __restrict__ dinv,
                                                   const float* __restrict__ A1, const float* __restrict__ B1,
                                                   float* __restrict__ h1p, int n) {
    __shared__ float facc[BW * FS1];   // 33.3 KB
    __shared__ float sA[HID], sB[HID];
    __shared__ float ldinv[BW];
    int b = blockIdx.x, tid = threadIdx.x;
    int base = b * CAP, len = gcursor[b];
    int node0 = b * BW;
    int nn = min(BW, n - node0);
    if (tid < HID) { sA[tid] = A1[tid]; sB[tid] = B1[tid]; }
    if (tid < nn) ldinv[tid] = dinv[node0 + tid];
    const __half2* htp = (const __half2*)ht1;   // [n][32] half2
    // init: self term
    for (int idx = tid; idx < nn * 32; idx += 256) {
        int row = idx >> 5, cp = idx & 31;
        float2 f = __half22float2(htp[(size_t)(node0 + row) * 32 + cp]);
        facc[row * FS1 + cp * 2] = f.x;
        facc[row * FS1 + cp * 2 + 1] = f.y;
    }
    __syncthreads();
    // edge phase: 2 edges per wave-instr, 4x unroll
    int wid = tid >> 6, lane = tid & 63;
    int eh = lane >> 5;
    int cp = lane & 31;             // half2 column
    int col2 = cp * 2;
    const unsigned* eb = ebuf + base;
    int i = wid * 2 + eh;
    for (; i + 24 < len; i += 32) {
        unsigned u0 = eb[i], u1 = eb[i + 8], u2 = eb[i + 16], u3 = eb[i + 24];
        float2 f0 = __half22float2(htp[(size_t)(u0 & 0x1FFFFu) * 32 + cp]);
        float2 f1 = __half22float2(htp[(size_t)(u1 & 0x1FFFFu) * 32 + cp]);
        float2 f2 = __half22float2(htp[(size_t)(u2 & 0x1FFFFu) * 32 + cp]);
        float2 f3 = __half22float2(htp[(size_t)(u3 & 0x1FFFFu) * 32 + cp]);
        atomicAdd(&facc[(u0 >> 17) * FS1 + col2], f0.x);
        atomicAdd(&facc[(u0 >> 17) * FS1 + col2 + 1], f0.y);
        atomicAdd(&facc[(u1 >> 17) * FS1 + col2], f1.x);
        atomicAdd(&facc[(u1 >> 17) * FS1 + col2 + 1], f1.y);
        atomicAdd(&facc[(u2 >> 17) * FS1 + col2], f2.x);
        atomicAdd(&facc[(u2 >> 17) * FS1 + col2 + 1], f2.y);
        atomicAdd(&facc[(u3 >> 17) * FS1 + col2], f3.x);
        atomicAdd(&facc[(u3 >> 17) * FS1 + col2 + 1], f3.y);
    }
    for (; i < len; i += 8) {
        unsigned u = eb[i];
        float2 f = __half22float2(htp[(size_t)(u & 0x1FFFFu) * 32 + cp]);
        atomicAdd(&facc[(u >> 17) * FS1 + col2], f.x);
        atomicAdd(&facc[(u >> 17) * FS1 + col2 + 1], f.y);
    }
    __syncthreads();
    // final: BN + ReLU, write f32 h1p
    for (int idx = tid; idx < nn * 32; idx += 256) {
        int row = idx >> 5, cc = (idx & 31) * 2;
        float d = ldinv[row];
        float2 fr = *(float2*)&facc[row * FS1 + cc];
        float2 o;
        o.x = fmaxf(fmaf(fr.x * d, sA[cc], sB[cc]), 0.f);
        o.y = fmaxf(fmaf(fr.y * d, sA[cc + 1], sB[cc + 1]), 0.f);
        *(float2*)&h1p[(size_t)(node0 + row) * HID + cc] = o;
    }
}

// ---------------- agg2 (edge-parallel) + classifier + log_softmax ----------------
#define FS2 33
__global__ __launch_bounds__(256) void agg2_kernel(const __half* __restrict__ ht2, const unsigned* __restrict__ ebuf,
                                                   const int* __restrict__ gcursor, const float* __restrict__ dinv,
                                                   const float* __restrict__ A2, const float* __restrict__ B2,
                                                   const float* __restrict__ Wc, const float* __restrict__ bc,
                                                   float* __restrict__ out, int n) {
    __shared__ float facc[BW * FS2];   // 16.9 KB
    __shared__ float sA[HID2], sB[HID2], sW[HID2 * 2];
    __shared__ float ldinv[BW];
    int b = blockIdx.x, tid = threadIdx.x;
    int base = b * CAP, len = gcursor[b];
    int node0 = b * BW;
    int nn = min(BW, n - node0);
    if (tid < HID2) { sA[tid] = A2[tid]; sB[tid] = B2[tid]; }
    if (tid >= 64 && tid < 64 + HID2 * 2) sW[tid - 64] = Wc[tid - 64];
    if (tid < nn) ldinv[tid] = dinv[node0 + tid];
    const __half2* htp = (const __half2*)ht2;   // [n][16] half2
    for (int idx = tid; idx < nn * 16; idx += 256) {
        int row = idx >> 4, cp = idx & 15;
        float2 f = __half22float2(htp[(size_t)(node0 + row) * 16 + cp]);
        facc[row * FS2 + cp * 2] = f.x;
        facc[row * FS2 + cp * 2 + 1] = f.y;
    }
    __syncthreads();
    // edge phase: 4 edges per wave-instr, 4x unroll
    int wid = tid >> 6, lane = tid & 63;
    int eq = lane >> 4;
    int cp = lane & 15;
    int col2 = cp * 2;
    const unsigned* eb = ebuf + base;
    int i = wid * 4 + eq;
    for (; i + 48 < len; i += 64) {
        unsigned u0 = eb[i], u1 = eb[i + 16], u2 = eb[i + 32], u3 = eb[i + 48];
        float2 f0 = __half22float2(htp[(size_t)(u0 & 0x1FFFFu) * 16 + cp]);
        float2 f1 = __half22float2(htp[(size_t)(u1 & 0x1FFFFu) * 16 + cp]);
        float2 f2 = __half22float2(htp[(size_t)(u2 & 0x1FFFFu) * 16 + cp]);
        float2 f3 = __half22float2(htp[(size_t)(u3 & 0x1FFFFu) * 16 + cp]);
        atomicAdd(&facc[(u0 >> 17) * FS2 + col2], f0.x);
        atomicAdd(&facc[(u0 >> 17) * FS2 + col2 + 1], f0.y);
        atomicAdd(&facc[(u1 >> 17) * FS2 + col2], f1.x);
        atomicAdd(&facc[(u1 >> 17) * FS2 + col2 + 1], f1.y);
        atomicAdd(&facc[(u2 >> 17) * FS2 + col2], f2.x);
        atomicAdd(&facc[(u2 >> 17) * FS2 + col2 + 1], f2.y);
        atomicAdd(&facc[(u3 >> 17) * FS2 + col2], f3.x);
        atomicAdd(&facc[(u3 >> 17) * FS2 + col2 + 1], f3.y);
    }
    for (; i < len; i += 16) {
        unsigned u = eb[i];
        float2 f = __half22float2(htp[(size_t)(u & 0x1FFFFu) * 16 + cp]);
        atomicAdd(&facc[(u >> 17) * FS2 + col2], f.x);
        atomicAdd(&facc[(u >> 17) * FS2 + col2 + 1], f.y);
    }
    __syncthreads();
    // final: BN + ReLU + classifier + log_softmax, one thread per node
    if (tid < nn) {
        float d = ldinv[tid];
        float p0 = 0.f, p1 = 0.f;
#pragma unroll
        for (int c = 0; c < HID2; c++) {
            float v = fmaxf(fmaf(facc[tid * FS2 + c] * d, sA[c], sB[c]), 0.f);
            p0 = fmaf(v, sW[c * 2 + 0], p0);
            p1 = fmaf(v, sW[c * 2 + 1], p1);
        }
        float l0 = p0 + bc[0], l1 = p1 + bc[1];
        float m = fmaxf(l0, l1);
        float lse = m + logf(expf(l0 - m) + expf(l1 - m));
        float2 o; o.x = l0 - lse; o.y = l1 - lse;
        *(float2*)&out[(size_t)(node0 + tid) * 2] = o;
    }
}

extern "C" void kernel_launch(void* const* d_in, const int* in_sizes, int n_in,
                              void* d_out, int out_size, void* d_ws, size_t ws_size,
                              hipStream_t stream) {
    const float* x   = (const float*)d_in[0];
    const int*   ei  = (const int*)d_in[1];     // harness converts int64 -> int32
    const float* W1  = (const float*)d_in[2];
    const float* b1  = (const float*)d_in[3];
    const float* W2  = (const float*)d_in[4];
    const float* b2  = (const float*)d_in[5];
    const float* g1  = (const float*)d_in[6];
    const float* be1 = (const float*)d_in[7];
    const float* rm1 = (const float*)d_in[8];
    const float* rv1 = (const float*)d_in[9];
    const float* g2  = (const float*)d_in[10];
    const float* be2 = (const float*)d_in[11];
    const float* rm2 = (const float*)d_in[12];
    const float* rv2 = (const float*)d_in[13];
    const float* Wc  = (const float*)d_in[14];
    const float* bc  = (const float*)d_in[15];
    float* out = (float*)d_out;

    int n = in_sizes[0] / F_IN;   // 100000
    int E = in_sizes[1] / 2;      // 1600000
    const int* srcv = ei;
    const int* dstv = ei + E;
    int NB = (n + BW - 1) / BW;   // 782

    char* ws = (char*)d_ws;
    size_t off = 0;
    auto alloc = [&](size_t bytes) -> char* {
        char* r = ws + off;
        off = (off + bytes + 511) & ~(size_t)511;
        return r;
    };
    int*      gcursor = (int*)alloc((size_t)NB * 4);
    float*    dinv    = (float*)alloc((size_t)n * 4);
    float*    A1 = (float*)alloc(HID * 4);
    float*    B1 = (float*)alloc(HID * 4);
    float*    A2 = (float*)alloc(HID2 * 4);
    float*    B2 = (float*)alloc(HID2 * 4);
    unsigned* ebuf = (unsigned*)alloc((size_t)NB * CAP * 4);  // ~8 MB, (dl<<17|src) records
    __half*   ht1  = (__half*)alloc((size_t)n * HID * 2);     // fp16 gather table
    float*    h1p  = (float*)alloc((size_t)n * HID * 4);
    __half*   ht2  = ht1;  // ht1 dead after agg1; reuse region

    hipMemsetAsync(gcursor, 0, (size_t)NB * 4, stream);

    int nch = (E + CH - 1) / CH;  // 196
    partition_kernel<<<nch, 1024, 0, stream>>>(srcv, dstv, E, gcursor, ebuf);
    degree_kernel<<<NB, 256, 0, stream>>>(ebuf, gcursor, dinv, n);
    constprep_kernel<<<1, 64, 0, stream>>>(g1, be1, rm1, rv1, b1, g2, be2, rm2, rv2, b2, A1, B1, A2, B2);

    int ngb = (n + 63) / 64;      // 1563
    gemm1_kernel<<<ngb, 256, 0, stream>>>(x, W1, dinv, ht1, n);
    agg1_kernel<<<NB, 256, 0, stream>>>(ht1, ebuf, gcursor, dinv, A1, B1, h1p, n);
    gemm2_kernel<<<ngb, 256, 0, stream>>>(h1p, W2, dinv, ht2, n);
    agg2_kernel<<<NB, 256, 0, stream>>>(ht2, ebuf, gcursor, dinv, A2, B2, Wc, bc, out, n);
}

// Round 8
// 301.275 us; speedup vs baseline: 3.9842x; 3.9842x over previous
//
#include <hip/hip_runtime.h>
#include <hip/hip_fp16.h>
#include <math.h>

#define F_IN 128
#define HID 64
#define HID2 32
#define EPS_BN 1e-5f
#define BW 128          // nodes per bucket
#define NBMAX 1024      // padded bucket count (actual NB = 782)
#define CAP 2560        // max edges per bucket (mean ~2046, +11 sigma)
#define CH 8192         // edges per partition workgroup

// ---------------- phase A: chunk counting-sort into bucket regions (1024 thr) ----------------
__global__ __launch_bounds__(1024) void partition_kernel(const int* __restrict__ src, const int* __restrict__ dst,
                                                         int E, int* __restrict__ gcursor,
                                                         unsigned* __restrict__ ebuf) {
    __shared__ int hist[NBMAX];
    __shared__ int start[NBMAX];
    __shared__ int cur[NBMAX];
    __shared__ int gb[NBMAX];
    __shared__ int sc[1024];
    __shared__ unsigned buf[CH];  // 32 KB
    int tid = threadIdx.x;
    int e0 = blockIdx.x * CH;
    hist[tid] = 0;
    __syncthreads();
#pragma unroll
    for (int it = 0; it < CH / 1024; it++) {
        int e = e0 + tid + it * 1024;
        if (e < E) atomicAdd(&hist[dst[e] >> 7], 1);
    }
    __syncthreads();
    int v = hist[tid];
    sc[tid] = v;
    __syncthreads();
    for (int off = 1; off < 1024; off <<= 1) {
        int t = (tid >= off) ? sc[tid - off] : 0;
        __syncthreads();
        sc[tid] += t;
        __syncthreads();
    }
    int ex = sc[tid] - v;  // exclusive prefix over buckets
    start[tid] = ex;
    cur[tid] = ex;
    gb[tid] = v ? atomicAdd(&gcursor[tid], v) : 0;   // reserve run in bucket region
    __syncthreads();
#pragma unroll
    for (int it = 0; it < CH / 1024; it++) {
        int e = e0 + tid + it * 1024;
        if (e < E) {
            int d = dst[e], s = src[e];
            int p = atomicAdd(&cur[d >> 7], 1);
            buf[p] = ((unsigned)(d & (BW - 1)) << 17) | (unsigned)s;  // src < 2^17
        }
    }
    __syncthreads();
    // write phase: 256 quad-groups x 4 buckets each
    int grp = tid >> 2, sub = tid & 3;
    for (int b = grp; b < NBMAX; b += 256) {
        int len = hist[b];
        if (!len) continue;
        int st = start[b];
        unsigned* dp = ebuf + (size_t)b * CAP + gb[b];
        for (int i = sub; i < len; i += 4) dp[i] = buf[st + i];
    }
}

// ---------------- phase B: per-bucket local sort; emits ns/ne/dinv and csr (in-place) ----------------
__global__ __launch_bounds__(256) void localsort_kernel(unsigned* __restrict__ ebuf, const int* __restrict__ gcursor,
                                                        int* __restrict__ ns, int* __restrict__ ne,
                                                        float* __restrict__ dinv, int n) {
    __shared__ unsigned lbuf[CAP];
    __shared__ int lhist[BW];
    __shared__ int lcur[BW];
    __shared__ int stmp[256];
    int b = blockIdx.x;
    int tid = threadIdx.x;
    int base = b * CAP;
    int len = gcursor[b];
    int node0 = b * BW;
    int nn = min(BW, n - node0);
    if (tid < BW) lhist[tid] = 0;
    __syncthreads();
    for (int k = tid; k < len; k += 256) {
        unsigned u = ebuf[base + k];
        lbuf[k] = u;
        atomicAdd(&lhist[u >> 17], 1);
    }
    __syncthreads();
    int v = (tid < BW) ? lhist[tid] : 0;
    stmp[tid] = v;
    __syncthreads();
    for (int off = 1; off < 256; off <<= 1) {
        int t = (tid >= off) ? stmp[tid - off] : 0;
        __syncthreads();
        stmp[tid] += t;
        __syncthreads();
    }
    int ex = stmp[tid] - v;  // exclusive within bucket
    if (tid < BW) lcur[tid] = ex;
    if (tid < nn) {
        ns[node0 + tid] = base + ex;
        ne[node0 + tid] = base + ex + v;
        dinv[node0 + tid] = rsqrtf((float)(v + 1));   // +1 self-loop
    }
    __syncthreads();
    for (int k = tid; k < len; k += 256) {
        unsigned u = lbuf[k];
        int p = atomicAdd(&lcur[u >> 17], 1);
        ebuf[base + p] = u & 0x1FFFFu;               // store global src id
    }
}

// ---------------- fold BN(eval)+bias into per-column scale/shift ----------------
__global__ void constprep_kernel(const float* g1, const float* be1, const float* rm1, const float* rv1, const float* b1,
                                 const float* g2, const float* be2, const float* rm2, const float* rv2, const float* b2,
                                 float* A1, float* B1, float* A2, float* B2) {
    int t = threadIdx.x;
    if (t < HID)  { float s = g1[t] * rsqrtf(rv1[t] + EPS_BN); A1[t] = s; B1[t] = (b1[t] - rm1[t]) * s + be1[t]; }
    if (t < HID2) { float s = g2[t] * rsqrtf(rv2[t] + EPS_BN); A2[t] = s; B2[t] = (b2[t] - rm2[t]) * s + be2[t]; }
}

// ---------------- GEMM1: ht1 = fp16( (x @ W1) * dinv[row] ) ----------------
#define XP1 132
__global__ __launch_bounds__(256) void gemm1_kernel(const float* __restrict__ x, const float* __restrict__ W1,
                                                    const float* __restrict__ dinv, __half* __restrict__ ht1,
                                                    int n) {
    __shared__ float wlds[F_IN * HID];   // 32 KB, [k][col]
    __shared__ float xlds[64 * XP1];     // 33.8 KB
    int tid = threadIdx.x;
    {
        const float4* wv = (const float4*)W1;
        float4* wl = (float4*)wlds;
#pragma unroll
        for (int i = 0; i < F_IN * HID / 4 / 256; i++) wl[tid + 256 * i] = wv[tid + 256 * i];
    }
    int row0 = blockIdx.x * 64;
    {
        const float4* xv = (const float4*)(x + (size_t)row0 * F_IN);
        int lim = (n - row0) * (F_IN / 4);
#pragma unroll
        for (int i = 0; i < 8; i++) {
            int f = tid + 256 * i;
            float4 v = make_float4(0.f, 0.f, 0.f, 0.f);
            if (f < lim) v = xv[f];
            int r = f >> 5, kp = (f & 31) * 4;
            *(float4*)&xlds[r * XP1 + kp] = v;
        }
    }
    __syncthreads();
    int col4 = (tid & 15) * 4;
    int rowg = tid >> 4;
    float acc[4][4];
#pragma unroll
    for (int r = 0; r < 4; r++)
#pragma unroll
        for (int c = 0; c < 4; c++) acc[r][c] = 0.f;
#pragma unroll 4
    for (int k = 0; k < F_IN; k += 4) {
        float4 wb[4];
#pragma unroll
        for (int j = 0; j < 4; j++) wb[j] = *(const float4*)&wlds[(k + j) * HID + col4];
#pragma unroll
        for (int r = 0; r < 4; r++) {
            float4 xa = *(const float4*)&xlds[(rowg * 4 + r) * XP1 + k];
            acc[r][0] = fmaf(xa.x, wb[0].x, acc[r][0]); acc[r][1] = fmaf(xa.x, wb[0].y, acc[r][1]);
            acc[r][2] = fmaf(xa.x, wb[0].z, acc[r][2]); acc[r][3] = fmaf(xa.x, wb[0].w, acc[r][3]);
            acc[r][0] = fmaf(xa.y, wb[1].x, acc[r][0]); acc[r][1] = fmaf(xa.y, wb[1].y, acc[r][1]);
            acc[r][2] = fmaf(xa.y, wb[1].z, acc[r][2]); acc[r][3] = fmaf(xa.y, wb[1].w, acc[r][3]);
            acc[r][0] = fmaf(xa.z, wb[2].x, acc[r][0]); acc[r][1] = fmaf(xa.z, wb[2].y, acc[r][1]);
            acc[r][2] = fmaf(xa.z, wb[2].z, acc[r][2]); acc[r][3] = fmaf(xa.z, wb[2].w, acc[r][3]);
            acc[r][0] = fmaf(xa.w, wb[3].x, acc[r][0]); acc[r][1] = fmaf(xa.w, wb[3].y, acc[r][1]);
            acc[r][2] = fmaf(xa.w, wb[3].z, acc[r][2]); acc[r][3] = fmaf(xa.w, wb[3].w, acc[r][3]);
        }
    }
    int rbase = row0 + rowg * 4;
#pragma unroll
    for (int r = 0; r < 4; r++) {
        int row = rbase + r;
        if (row < n) {
            float d = dinv[row];
            __half2 h0, h1;
            h0.x = __float2half(acc[r][0] * d); h0.y = __float2half(acc[r][1] * d);
            h1.x = __float2half(acc[r][2] * d); h1.y = __float2half(acc[r][3] * d);
            __half2* dp = (__half2*)(ht1 + (size_t)row * HID + col4);
            dp[0] = h0; dp[1] = h1;
        }
    }
}

// ---------------- GEMM2: ht2 = fp16( (h1p @ W2) * dinv[row] ) ----------------
#define XP2 68
__global__ __launch_bounds__(256) void gemm2_kernel(const float* __restrict__ h1p, const float* __restrict__ W2,
                                                    const float* __restrict__ dinv, __half* __restrict__ ht2,
                                                    int n) {
    __shared__ float wlds[HID * HID2];   // 8 KB, [k][col]
    __shared__ float xlds[64 * XP2];     // 17.4 KB
    int tid = threadIdx.x;
    {
        const float4* wv = (const float4*)W2;
        float4* wl = (float4*)wlds;
#pragma unroll
        for (int i = 0; i < HID * HID2 / 4 / 256; i++) wl[tid + 256 * i] = wv[tid + 256 * i];
    }
    int row0 = blockIdx.x * 64;
    {
        const float4* xv = (const float4*)(h1p + (size_t)row0 * HID);
        int lim = (n - row0) * (HID / 4);
#pragma unroll
        for (int i = 0; i < 4; i++) {
            int f = tid + 256 * i;
            float4 v = make_float4(0.f, 0.f, 0.f, 0.f);
            if (f < lim) v = xv[f];
            int r = f >> 4, kp = (f & 15) * 4;
            *(float4*)&xlds[r * XP2 + kp] = v;
        }
    }
    __syncthreads();
    int col4 = (tid & 7) * 4;
    int rowg = tid >> 3;
    float acc[2][4];
#pragma unroll
    for (int r = 0; r < 2; r++)
#pragma unroll
        for (int c = 0; c < 4; c++) acc[r][c] = 0.f;
#pragma unroll 4
    for (int k = 0; k < HID; k += 4) {
        float4 wb[4];
#pragma unroll
        for (int j = 0; j < 4; j++) wb[j] = *(const float4*)&wlds[(k + j) * HID2 + col4];
#pragma unroll
        for (int r = 0; r < 2; r++) {
            float4 xa = *(const float4*)&xlds[(rowg * 2 + r) * XP2 + k];
            acc[r][0] = fmaf(xa.x, wb[0].x, acc[r][0]); acc[r][1] = fmaf(xa.x, wb[0].y, acc[r][1]);
            acc[r][2] = fmaf(xa.x, wb[0].z, acc[r][2]); acc[r][3] = fmaf(xa.x, wb[0].w, acc[r][3]);
            acc[r][0] = fmaf(xa.y, wb[1].x, acc[r][0]); acc[r][1] = fmaf(xa.y, wb[1].y, acc[r][1]);
            acc[r][2] = fmaf(xa.y, wb[1].z, acc[r][2]); acc[r][3] = fmaf(xa.y, wb[1].w, acc[r][3]);
            acc[r][0] = fmaf(xa.z, wb[2].x, acc[r][0]); acc[r][1] = fmaf(xa.z, wb[2].y, acc[r][1]);
            acc[r][2] = fmaf(xa.z, wb[2].z, acc[r][2]); acc[r][3] = fmaf(xa.z, wb[2].w, acc[r][3]);
            acc[r][0] = fmaf(xa.w, wb[3].x, acc[r][0]); acc[r][1] = fmaf(xa.w, wb[3].y, acc[r][1]);
            acc[r][2] = fmaf(xa.w, wb[3].z, acc[r][2]); acc[r][3] = fmaf(xa.w, wb[3].w, acc[r][3]);
        }
    }
    int rbase = row0 + rowg * 2;
#pragma unroll
    for (int r = 0; r < 2; r++) {
        int row = rbase + r;
        if (row < n) {
            float d = dinv[row];
            __half2 h0, h1;
            h0.x = __float2half(acc[r][0] * d); h0.y = __float2half(acc[r][1] * d);
            h1.x = __float2half(acc[r][2] * d); h1.y = __float2half(acc[r][3] * d);
            __half2* dp = (__half2*)(ht2 + (size_t)row * HID2 + col4);
            dp[0] = h0; dp[1] = h1;
        }
    }
}

// ---------------- agg1: node-parallel, half2 lanes -> 2 rows per gather instr ----------------
// wave = 1 node; eh = lane>>5 edge-parity, cp = lane&31 half2-column
__global__ __launch_bounds__(256) void agg1_kernel(const __half* __restrict__ ht1, const int* __restrict__ ns,
                                                   const int* __restrict__ ne, const int* __restrict__ csr,
                                                   const float* __restrict__ dinv,
                                                   const float* __restrict__ A1, const float* __restrict__ B1,
                                                   float* __restrict__ h1p, int n) {
    int node = (blockIdx.x * blockDim.x + threadIdx.x) >> 6;
    if (node >= n) return;
    int lane = threadIdx.x & 63;
    int eh = lane >> 5, cp = lane & 31;
    const __half2* htp = (const __half2*)ht1;   // [n][32] half2
    int s = ns[node], e_end = ne[node];
    float ax = 0.f, ay = 0.f;
    if (eh == 0) {  // self-loop term counted once
        float2 f = __half22float2(htp[(size_t)node * 32 + cp]);
        ax = f.x; ay = f.y;
    }
    int i = s + eh;
    for (; i + 14 < e_end; i += 16) {   // 8 gathers in flight/lane; wave covers 16 rows
        int i0 = csr[i + 0], i1 = csr[i + 2], i2 = csr[i + 4], i3 = csr[i + 6];
        int i4 = csr[i + 8], i5 = csr[i + 10], i6 = csr[i + 12], i7 = csr[i + 14];
        float2 f0 = __half22float2(htp[(size_t)i0 * 32 + cp]);
        float2 f1 = __half22float2(htp[(size_t)i1 * 32 + cp]);
        float2 f2 = __half22float2(htp[(size_t)i2 * 32 + cp]);
        float2 f3 = __half22float2(htp[(size_t)i3 * 32 + cp]);
        float2 f4 = __half22float2(htp[(size_t)i4 * 32 + cp]);
        float2 f5 = __half22float2(htp[(size_t)i5 * 32 + cp]);
        float2 f6 = __half22float2(htp[(size_t)i6 * 32 + cp]);
        float2 f7 = __half22float2(htp[(size_t)i7 * 32 + cp]);
        ax += ((f0.x + f1.x) + (f2.x + f3.x)) + ((f4.x + f5.x) + (f6.x + f7.x));
        ay += ((f0.y + f1.y) + (f2.y + f3.y)) + ((f4.y + f5.y) + (f6.y + f7.y));
    }
    for (; i < e_end; i += 2) {
        float2 f = __half22float2(htp[(size_t)csr[i] * 32 + cp]);
        ax += f.x; ay += f.y;
    }
    ax += __shfl_xor(ax, 32);
    ay += __shfl_xor(ay, 32);
    if (eh == 0) {
        float d = dinv[node];
        int c0 = cp * 2;
        float2 o;
        o.x = fmaxf(fmaf(ax * d, A1[c0], B1[c0]), 0.f);
        o.y = fmaxf(fmaf(ay * d, A1[c0 + 1], B1[c0 + 1]), 0.f);
        *(float2*)&h1p[(size_t)node * HID + c0] = o;
    }
}

// ---------------- agg2: node-parallel half2 (4 rows/instr) + classifier + log_softmax ----------------
// eq = lane>>4 edge-quad, cp = lane&15 half2-column
__global__ __launch_bounds__(256) void agg2_kernel(const __half* __restrict__ ht2, const int* __restrict__ ns,
                                                   const int* __restrict__ ne, const int* __restrict__ csr,
                                                   const float* __restrict__ dinv,
                                                   const float* __restrict__ A2, const float* __restrict__ B2,
                                                   const float* __restrict__ Wc, const float* __restrict__ bc,
                                                   float* __restrict__ out, int n) {
    int node = (blockIdx.x * blockDim.x + threadIdx.x) >> 6;
    if (node >= n) return;
    int lane = threadIdx.x & 63;
    int eq = lane >> 4, cp = lane & 15;
    const __half2* htp = (const __half2*)ht2;   // [n][16] half2
    int s = ns[node], e_end = ne[node];
    float ax = 0.f, ay = 0.f;
    if (eq == 0) {
        float2 f = __half22float2(htp[(size_t)node * 16 + cp]);
        ax = f.x; ay = f.y;
    }
    int i = s + eq;
    for (; i + 12 < e_end; i += 16) {   // 4 gathers in flight/lane; wave covers 16 rows
        int i0 = csr[i + 0], i1 = csr[i + 4], i2 = csr[i + 8], i3 = csr[i + 12];
        float2 f0 = __half22float2(htp[(size_t)i0 * 16 + cp]);
        float2 f1 = __half22float2(htp[(size_t)i1 * 16 + cp]);
        float2 f2 = __half22float2(htp[(size_t)i2 * 16 + cp]);
        float2 f3 = __half22float2(htp[(size_t)i3 * 16 + cp]);
        ax += (f0.x + f1.x) + (f2.x + f3.x);
        ay += (f0.y + f1.y) + (f2.y + f3.y);
    }
    for (; i < e_end; i += 4) {
        float2 f = __half22float2(htp[(size_t)csr[i] * 16 + cp]);
        ax += f.x; ay += f.y;
    }
    ax += __shfl_xor(ax, 32); ay += __shfl_xor(ay, 32);
    ax += __shfl_xor(ax, 16); ay += __shfl_xor(ay, 16);
    // all lanes hold full sums for cols 2cp, 2cp+1
    float d = dinv[node];
    int c0 = cp * 2;
    float v0 = fmaxf(fmaf(ax * d, A2[c0], B2[c0]), 0.f);
    float v1 = fmaxf(fmaf(ay * d, A2[c0 + 1], B2[c0 + 1]), 0.f);
    float p0 = v0 * Wc[c0 * 2 + 0] + v1 * Wc[c0 * 2 + 2];
    float p1 = v0 * Wc[c0 * 2 + 1] + v1 * Wc[c0 * 2 + 3];
#pragma unroll
    for (int off = 8; off >= 1; off >>= 1) { p0 += __shfl_xor(p0, off); p1 += __shfl_xor(p1, off); }
    if (lane == 0) {
        float l0 = p0 + bc[0], l1 = p1 + bc[1];
        float m = fmaxf(l0, l1);
        float lse = m + logf(expf(l0 - m) + expf(l1 - m));
        float2 o; o.x = l0 - lse; o.y = l1 - lse;
        *(float2*)&out[(size_t)node * 2] = o;
    }
}

extern "C" void kernel_launch(void* const* d_in, const int* in_sizes, int n_in,
                              void* d_out, int out_size, void* d_ws, size_t ws_size,
                              hipStream_t stream) {
    const float* x   = (const float*)d_in[0];
    const int*   ei  = (const int*)d_in[1];     // harness converts int64 -> int32
    const float* W1  = (const float*)d_in[2];
    const float* b1  = (const float*)d_in[3];
    const float* W2  = (const float*)d_in[4];
    const float* b2  = (const float*)d_in[5];
    const float* g1  = (const float*)d_in[6];
    const float* be1 = (const float*)d_in[7];
    const float* rm1 = (const float*)d_in[8];
    const float* rv1 = (const float*)d_in[9];
    const float* g2  = (const float*)d_in[10];
    const float* be2 = (const float*)d_in[11];
    const float* rm2 = (const float*)d_in[12];
    const float* rv2 = (const float*)d_in[13];
    const float* Wc  = (const float*)d_in[14];
    const float* bc  = (const float*)d_in[15];
    float* out = (float*)d_out;

    int n = in_sizes[0] / F_IN;   // 100000
    int E = in_sizes[1] / 2;      // 1600000
    const int* srcv = ei;
    const int* dstv = ei + E;
    int NB = (n + BW - 1) / BW;   // 782

    char* ws = (char*)d_ws;
    size_t off = 0;
    auto alloc = [&](size_t bytes) -> char* {
        char* r = ws + off;
        off = (off + bytes + 511) & ~(size_t)511;
        return r;
    };
    int*      gcursor = (int*)alloc((size_t)NB * 4);
    int*      ns      = (int*)alloc((size_t)n * 4);
    int*      ne      = (int*)alloc((size_t)n * 4);
    float*    dinv    = (float*)alloc((size_t)n * 4);
    float*    A1 = (float*)alloc(HID * 4);
    float*    B1 = (float*)alloc(HID * 4);
    float*    A2 = (float*)alloc(HID2 * 4);
    float*    B2 = (float*)alloc(HID2 * 4);
    unsigned* ebuf = (unsigned*)alloc((size_t)NB * CAP * 4);  // ~8 MB; becomes csr in-place
    __half*   ht1  = (__half*)alloc((size_t)n * HID * 2);     // fp16 gather table
    float*    h1p  = (float*)alloc((size_t)n * HID * 4);
    __half*   ht2  = ht1;  // ht1 dead after agg1; reuse region

    hipMemsetAsync(gcursor, 0, (size_t)NB * 4, stream);

    int nch = (E + CH - 1) / CH;  // 196
    partition_kernel<<<nch, 1024, 0, stream>>>(srcv, dstv, E, gcursor, ebuf);
    localsort_kernel<<<NB, 256, 0, stream>>>(ebuf, gcursor, ns, ne, dinv, n);
    constprep_kernel<<<1, 64, 0, stream>>>(g1, be1, rm1, rv1, b1, g2, be2, rm2, rv2, b2, A1, B1, A2, B2);

    int ngb = (n + 63) / 64;      // 1563
    gemm1_kernel<<<ngb, 256, 0, stream>>>(x, W1, dinv, ht1, n);
    agg1_kernel<<<(n + 3) / 4, 256, 0, stream>>>(ht1, ns, ne, (const int*)ebuf, dinv, A1, B1, h1p, n);
    gemm2_kernel<<<ngb, 256, 0, stream>>>(h1p, W2, dinv, ht2, n);
    agg2_kernel<<<(n + 3) / 4, 256, 0, stream>>>(ht2, ns, ne, (const int*)ebuf, dinv, A2, B2, Wc, bc, out, n);
}

// Round 9
// 269.358 us; speedup vs baseline: 4.4563x; 1.1185x over previous
//
#include <hip/hip_runtime.h>
#include <hip/hip_fp16.h>
#include <math.h>

#define F_IN 128
#define HID 64
#define HID2 32
#define EPS_BN 1e-5f
#define BW 128          // nodes per bucket
#define NBMAX 1024      // padded bucket count (actual NB = 782)
#define CAP 2560        // max edges per bucket (mean ~2046, +11 sigma)
#define CH 8192         // edges per partition workgroup

// ---------------- phase A: chunk counting-sort into bucket regions (1024 thr) ----------------
__global__ __launch_bounds__(1024) void partition_kernel(const int* __restrict__ src, const int* __restrict__ dst,
                                                         int E, int* __restrict__ gcursor,
                                                         unsigned* __restrict__ ebuf) {
    __shared__ int hist[NBMAX];
    __shared__ int start[NBMAX];
    __shared__ int cur[NBMAX];
    __shared__ int gb[NBMAX];
    __shared__ int sc[1024];
    __shared__ unsigned buf[CH];  // 32 KB
    int tid = threadIdx.x;
    int e0 = blockIdx.x * CH;
    hist[tid] = 0;
    __syncthreads();
#pragma unroll
    for (int it = 0; it < CH / 1024; it++) {
        int e = e0 + tid + it * 1024;
        if (e < E) atomicAdd(&hist[dst[e] >> 7], 1);
    }
    __syncthreads();
    int v = hist[tid];
    sc[tid] = v;
    __syncthreads();
    for (int off = 1; off < 1024; off <<= 1) {
        int t = (tid >= off) ? sc[tid - off] : 0;
        __syncthreads();
        sc[tid] += t;
        __syncthreads();
    }
    int ex = sc[tid] - v;  // exclusive prefix over buckets
    start[tid] = ex;
    cur[tid] = ex;
    gb[tid] = v ? atomicAdd(&gcursor[tid], v) : 0;   // reserve run in bucket region
    __syncthreads();
#pragma unroll
    for (int it = 0; it < CH / 1024; it++) {
        int e = e0 + tid + it * 1024;
        if (e < E) {
            int d = dst[e], s = src[e];
            int p = atomicAdd(&cur[d >> 7], 1);
            buf[p] = ((unsigned)(d & (BW - 1)) << 17) | (unsigned)s;  // src < 2^17
        }
    }
    __syncthreads();
    // write phase: 256 quad-groups x 4 buckets each
    int grp = tid >> 2, sub = tid & 3;
    for (int b = grp; b < NBMAX; b += 256) {
        int len = hist[b];
        if (!len) continue;
        int st = start[b];
        unsigned* dp = ebuf + (size_t)b * CAP + gb[b];
        for (int i = sub; i < len; i += 4) dp[i] = buf[st + i];
    }
}

// ---------------- phase B: per-bucket local sort; emits ns/ne/dinv and csr (in-place) ----------------
__global__ __launch_bounds__(256) void localsort_kernel(unsigned* __restrict__ ebuf, const int* __restrict__ gcursor,
                                                        int* __restrict__ ns, int* __restrict__ ne,
                                                        float* __restrict__ dinv, int n) {
    __shared__ unsigned lbuf[CAP];
    __shared__ int lhist[BW];
    __shared__ int lcur[BW];
    __shared__ int stmp[256];
    int b = blockIdx.x;
    int tid = threadIdx.x;
    int base = b * CAP;
    int len = gcursor[b];
    int node0 = b * BW;
    int nn = min(BW, n - node0);
    if (tid < BW) lhist[tid] = 0;
    __syncthreads();
    for (int k = tid; k < len; k += 256) {
        unsigned u = ebuf[base + k];
        lbuf[k] = u;
        atomicAdd(&lhist[u >> 17], 1);
    }
    __syncthreads();
    int v = (tid < BW) ? lhist[tid] : 0;
    stmp[tid] = v;
    __syncthreads();
    for (int off = 1; off < 256; off <<= 1) {
        int t = (tid >= off) ? stmp[tid - off] : 0;
        __syncthreads();
        stmp[tid] += t;
        __syncthreads();
    }
    int ex = stmp[tid] - v;  // exclusive within bucket
    if (tid < BW) lcur[tid] = ex;
    if (tid < nn) {
        ns[node0 + tid] = base + ex;
        ne[node0 + tid] = base + ex + v;
        dinv[node0 + tid] = rsqrtf((float)(v + 1));   // +1 self-loop
    }
    __syncthreads();
    for (int k = tid; k < len; k += 256) {
        unsigned u = lbuf[k];
        int p = atomicAdd(&lcur[u >> 17], 1);
        ebuf[base + p] = u & 0x1FFFFu;               // store global src id
    }
}

// ---------------- fold BN(eval)+bias into per-column scale/shift ----------------
__global__ void constprep_kernel(const float* g1, const float* be1, const float* rm1, const float* rv1, const float* b1,
                                 const float* g2, const float* be2, const float* rm2, const float* rv2, const float* b2,
                                 float* A1, float* B1, float* A2, float* B2) {
    int t = threadIdx.x;
    if (t < HID)  { float s = g1[t] * rsqrtf(rv1[t] + EPS_BN); A1[t] = s; B1[t] = (b1[t] - rm1[t]) * s + be1[t]; }
    if (t < HID2) { float s = g2[t] * rsqrtf(rv2[t] + EPS_BN); A2[t] = s; B2[t] = (b2[t] - rm2[t]) * s + be2[t]; }
}

// ---------------- GEMM1: ht1 = fp16( (x @ W1) * dinv[row] ) ----------------
#define XP1 132
__global__ __launch_bounds__(256) void gemm1_kernel(const float* __restrict__ x, const float* __restrict__ W1,
                                                    const float* __restrict__ dinv, __half* __restrict__ ht1,
                                                    int n) {
    __shared__ float wlds[F_IN * HID];   // 32 KB, [k][col]
    __shared__ float xlds[64 * XP1];     // 33.8 KB
    int tid = threadIdx.x;
    {
        const float4* wv = (const float4*)W1;
        float4* wl = (float4*)wlds;
#pragma unroll
        for (int i = 0; i < F_IN * HID / 4 / 256; i++) wl[tid + 256 * i] = wv[tid + 256 * i];
    }
    int row0 = blockIdx.x * 64;
    {
        const float4* xv = (const float4*)(x + (size_t)row0 * F_IN);
        int lim = (n - row0) * (F_IN / 4);
#pragma unroll
        for (int i = 0; i < 8; i++) {
            int f = tid + 256 * i;
            float4 v = make_float4(0.f, 0.f, 0.f, 0.f);
            if (f < lim) v = xv[f];
            int r = f >> 5, kp = (f & 31) * 4;
            *(float4*)&xlds[r * XP1 + kp] = v;
        }
    }
    __syncthreads();
    int col4 = (tid & 15) * 4;
    int rowg = tid >> 4;
    float acc[4][4];
#pragma unroll
    for (int r = 0; r < 4; r++)
#pragma unroll
        for (int c = 0; c < 4; c++) acc[r][c] = 0.f;
#pragma unroll 4
    for (int k = 0; k < F_IN; k += 4) {
        float4 wb[4];
#pragma unroll
        for (int j = 0; j < 4; j++) wb[j] = *(const float4*)&wlds[(k + j) * HID + col4];
#pragma unroll
        for (int r = 0; r < 4; r++) {
            float4 xa = *(const float4*)&xlds[(rowg * 4 + r) * XP1 + k];
            acc[r][0] = fmaf(xa.x, wb[0].x, acc[r][0]); acc[r][1] = fmaf(xa.x, wb[0].y, acc[r][1]);
            acc[r][2] = fmaf(xa.x, wb[0].z, acc[r][2]); acc[r][3] = fmaf(xa.x, wb[0].w, acc[r][3]);
            acc[r][0] = fmaf(xa.y, wb[1].x, acc[r][0]); acc[r][1] = fmaf(xa.y, wb[1].y, acc[r][1]);
            acc[r][2] = fmaf(xa.y, wb[1].z, acc[r][2]); acc[r][3] = fmaf(xa.y, wb[1].w, acc[r][3]);
            acc[r][0] = fmaf(xa.z, wb[2].x, acc[r][0]); acc[r][1] = fmaf(xa.z, wb[2].y, acc[r][1]);
            acc[r][2] = fmaf(xa.z, wb[2].z, acc[r][2]); acc[r][3] = fmaf(xa.z, wb[2].w, acc[r][3]);
            acc[r][0] = fmaf(xa.w, wb[3].x, acc[r][0]); acc[r][1] = fmaf(xa.w, wb[3].y, acc[r][1]);
            acc[r][2] = fmaf(xa.w, wb[3].z, acc[r][2]); acc[r][3] = fmaf(xa.w, wb[3].w, acc[r][3]);
        }
    }
    int rbase = row0 + rowg * 4;
#pragma unroll
    for (int r = 0; r < 4; r++) {
        int row = rbase + r;
        if (row < n) {
            float d = dinv[row];
            __half2 h0, h1;
            h0.x = __float2half(acc[r][0] * d); h0.y = __float2half(acc[r][1] * d);
            h1.x = __float2half(acc[r][2] * d); h1.y = __float2half(acc[r][3] * d);
            __half2* dp = (__half2*)(ht1 + (size_t)row * HID + col4);
            dp[0] = h0; dp[1] = h1;
        }
    }
}

// ---------------- GEMM2: ht2 = fp16( (h1p @ W2) * dinv[row] ) ----------------
#define XP2 68
__global__ __launch_bounds__(256) void gemm2_kernel(const float* __restrict__ h1p, const float* __restrict__ W2,
                                                    const float* __restrict__ dinv, __half* __restrict__ ht2,
                                                    int n) {
    __shared__ float wlds[HID * HID2];   // 8 KB, [k][col]
    __shared__ float xlds[64 * XP2];     // 17.4 KB
    int tid = threadIdx.x;
    {
        const float4* wv = (const float4*)W2;
        float4* wl = (float4*)wlds;
#pragma unroll
        for (int i = 0; i < HID * HID2 / 4 / 256; i++) wl[tid + 256 * i] = wv[tid + 256 * i];
    }
    int row0 = blockIdx.x * 64;
    {
        const float4* xv = (const float4*)(h1p + (size_t)row0 * HID);
        int lim = (n - row0) * (HID / 4);
#pragma unroll
        for (int i = 0; i < 4; i++) {
            int f = tid + 256 * i;
            float4 v = make_float4(0.f, 0.f, 0.f, 0.f);
            if (f < lim) v = xv[f];
            int r = f >> 4, kp = (f & 15) * 4;
            *(float4*)&xlds[r * XP2 + kp] = v;
        }
    }
    __syncthreads();
    int col4 = (tid & 7) * 4;
    int rowg = tid >> 3;
    float acc[2][4];
#pragma unroll
    for (int r = 0; r < 2; r++)
#pragma unroll
        for (int c = 0; c < 4; c++) acc[r][c] = 0.f;
#pragma unroll 4
    for (int k = 0; k < HID; k += 4) {
        float4 wb[4];
#pragma unroll
        for (int j = 0; j < 4; j++) wb[j] = *(const float4*)&wlds[(k + j) * HID2 + col4];
#pragma unroll
        for (int r = 0; r < 2; r++) {
            float4 xa = *(const float4*)&xlds[(rowg * 2 + r) * XP2 + k];
            acc[r][0] = fmaf(xa.x, wb[0].x, acc[r][0]); acc[r][1] = fmaf(xa.x, wb[0].y, acc[r][1]);
            acc[r][2] = fmaf(xa.x, wb[0].z, acc[r][2]); acc[r][3] = fmaf(xa.x, wb[0].w, acc[r][3]);
            acc[r][0] = fmaf(xa.y, wb[1].x, acc[r][0]); acc[r][1] = fmaf(xa.y, wb[1].y, acc[r][1]);
            acc[r][2] = fmaf(xa.y, wb[1].z, acc[r][2]); acc[r][3] = fmaf(xa.y, wb[1].w, acc[r][3]);
            acc[r][0] = fmaf(xa.z, wb[2].x, acc[r][0]); acc[r][1] = fmaf(xa.z, wb[2].y, acc[r][1]);
            acc[r][2] = fmaf(xa.z, wb[2].z, acc[r][2]); acc[r][3] = fmaf(xa.z, wb[2].w, acc[r][3]);
            acc[r][0] = fmaf(xa.w, wb[3].x, acc[r][0]); acc[r][1] = fmaf(xa.w, wb[3].y, acc[r][1]);
            acc[r][2] = fmaf(xa.w, wb[3].z, acc[r][2]); acc[r][3] = fmaf(xa.w, wb[3].w, acc[r][3]);
        }
    }
    int rbase = row0 + rowg * 2;
#pragma unroll
    for (int r = 0; r < 2; r++) {
        int row = rbase + r;
        if (row < n) {
            float d = dinv[row];
            __half2 h0, h1;
            h0.x = __float2half(acc[r][0] * d); h0.y = __float2half(acc[r][1] * d);
            h1.x = __float2half(acc[r][2] * d); h1.y = __float2half(acc[r][3] * d);
            __half2* dp = (__half2*)(ht2 + (size_t)row * HID2 + col4);
            dp[0] = h0; dp[1] = h1;
        }
    }
}

// ---------------- agg1: node-parallel, predicated 16-edge blocks (no serial remainder) ----------------
// wave = 1 node; eh = lane>>5 edge-parity, cp = lane&31 half2-column
__global__ __launch_bounds__(256) void agg1_kernel(const __half* __restrict__ ht1, const int* __restrict__ ns,
                                                   const int* __restrict__ ne, const int* __restrict__ csr,
                                                   const float* __restrict__ dinv,
                                                   const float* __restrict__ A1, const float* __restrict__ B1,
                                                   float* __restrict__ h1p, int n) {
    int node = (blockIdx.x * blockDim.x + threadIdx.x) >> 6;
    if (node >= n) return;
    int lane = threadIdx.x & 63;
    int eh = lane >> 5, cp = lane & 31;
    const __half2* htp = (const __half2*)ht1;   // [n][32] half2
    int s = ns[node], e_end = ne[node];
    float ax = 0.f, ay = 0.f;
    if (eh == 0) {  // self-loop term counted once
        float2 f = __half22float2(htp[(size_t)node * 32 + cp]);
        ax = f.x; ay = f.y;
    }
    // fully predicated: ceil(d/16) blocks of 16 slots; invalid slots clamp to csr[s]
    // (clamped lanes all read the same line -> broadcast, ~free extra fetch)
    for (int i = s + eh; i < e_end; i += 16) {
        int idx[8];
        bool val[8];
#pragma unroll
        for (int j = 0; j < 8; j++) {
            int e = i + 2 * j;
            val[j] = e < e_end;
            idx[j] = csr[val[j] ? e : s];
        }
#pragma unroll
        for (int j = 0; j < 8; j++) {
            float2 f = __half22float2(htp[(size_t)idx[j] * 32 + cp]);
            ax += val[j] ? f.x : 0.f;
            ay += val[j] ? f.y : 0.f;
        }
    }
    ax += __shfl_xor(ax, 32);
    ay += __shfl_xor(ay, 32);
    if (eh == 0) {
        float d = dinv[node];
        int c0 = cp * 2;
        float2 o;
        o.x = fmaxf(fmaf(ax * d, A1[c0], B1[c0]), 0.f);
        o.y = fmaxf(fmaf(ay * d, A1[c0 + 1], B1[c0 + 1]), 0.f);
        *(float2*)&h1p[(size_t)node * HID + c0] = o;
    }
}

// ---------------- agg2: node-parallel, predicated 16-edge blocks + classifier + log_softmax ----------------
// eq = lane>>4 edge-quad, cp = lane&15 half2-column
__global__ __launch_bounds__(256) void agg2_kernel(const __half* __restrict__ ht2, const int* __restrict__ ns,
                                                   const int* __restrict__ ne, const int* __restrict__ csr,
                                                   const float* __restrict__ dinv,
                                                   const float* __restrict__ A2, const float* __restrict__ B2,
                                                   const float* __restrict__ Wc, const float* __restrict__ bc,
                                                   float* __restrict__ out, int n) {
    int node = (blockIdx.x * blockDim.x + threadIdx.x) >> 6;
    if (node >= n) return;
    int lane = threadIdx.x & 63;
    int eq = lane >> 4, cp = lane & 15;
    const __half2* htp = (const __half2*)ht2;   // [n][16] half2
    int s = ns[node], e_end = ne[node];
    float ax = 0.f, ay = 0.f;
    if (eq == 0) {
        float2 f = __half22float2(htp[(size_t)node * 16 + cp]);
        ax = f.x; ay = f.y;
    }
    for (int i = s + eq; i < e_end; i += 16) {
        int idx[4];
        bool val[4];
#pragma unroll
        for (int j = 0; j < 4; j++) {
            int e = i + 4 * j;
            val[j] = e < e_end;
            idx[j] = csr[val[j] ? e : s];
        }
#pragma unroll
        for (int j = 0; j < 4; j++) {
            float2 f = __half22float2(htp[(size_t)idx[j] * 16 + cp]);
            ax += val[j] ? f.x : 0.f;
            ay += val[j] ? f.y : 0.f;
        }
    }
    ax += __shfl_xor(ax, 32); ay += __shfl_xor(ay, 32);
    ax += __shfl_xor(ax, 16); ay += __shfl_xor(ay, 16);
    // all lanes hold full sums for cols 2cp, 2cp+1
    float d = dinv[node];
    int c0 = cp * 2;
    float v0 = fmaxf(fmaf(ax * d, A2[c0], B2[c0]), 0.f);
    float v1 = fmaxf(fmaf(ay * d, A2[c0 + 1], B2[c0 + 1]), 0.f);
    float p0 = v0 * Wc[c0 * 2 + 0] + v1 * Wc[c0 * 2 + 2];
    float p1 = v0 * Wc[c0 * 2 + 1] + v1 * Wc[c0 * 2 + 3];
#pragma unroll
    for (int off = 8; off >= 1; off >>= 1) { p0 += __shfl_xor(p0, off); p1 += __shfl_xor(p1, off); }
    if (lane == 0) {
        float l0 = p0 + bc[0], l1 = p1 + bc[1];
        float m = fmaxf(l0, l1);
        float lse = m + logf(expf(l0 - m) + expf(l1 - m));
        float2 o; o.x = l0 - lse; o.y = l1 - lse;
        *(float2*)&out[(size_t)node * 2] = o;
    }
}

extern "C" void kernel_launch(void* const* d_in, const int* in_sizes, int n_in,
                              void* d_out, int out_size, void* d_ws, size_t ws_size,
                              hipStream_t stream) {
    const float* x   = (const float*)d_in[0];
    const int*   ei  = (const int*)d_in[1];     // harness converts int64 -> int32
    const float* W1  = (const float*)d_in[2];
    const float* b1  = (const float*)d_in[3];
    const float* W2  = (const float*)d_in[4];
    const float* b2  = (const float*)d_in[5];
    const float* g1  = (const float*)d_in[6];
    const float* be1 = (const float*)d_in[7];
    const float* rm1 = (const float*)d_in[8];
    const float* rv1 = (const float*)d_in[9];
    const float* g2  = (const float*)d_in[10];
    const float* be2 = (const float*)d_in[11];
    const float* rm2 = (const float*)d_in[12];
    const float* rv2 = (const float*)d_in[13];
    const float* Wc  = (const float*)d_in[14];
    const float* bc  = (const float*)d_in[15];
    float* out = (float*)d_out;

    int n = in_sizes[0] / F_IN;   // 100000
    int E = in_sizes[1] / 2;      // 1600000
    const int* srcv = ei;
    const int* dstv = ei + E;
    int NB = (n + BW - 1) / BW;   // 782

    char* ws = (char*)d_ws;
    size_t off = 0;
    auto alloc = [&](size_t bytes) -> char* {
        char* r = ws + off;
        off = (off + bytes + 511) & ~(size_t)511;
        return r;
    };
    int*      gcursor = (int*)alloc((size_t)NB * 4);
    int*      ns      = (int*)alloc((size_t)n * 4);
    int*      ne      = (int*)alloc((size_t)n * 4);
    float*    dinv    = (float*)alloc((size_t)n * 4);
    float*    A1 = (float*)alloc(HID * 4);
    float*    B1 = (float*)alloc(HID * 4);
    float*    A2 = (float*)alloc(HID2 * 4);
    float*    B2 = (float*)alloc(HID2 * 4);
    unsigned* ebuf = (unsigned*)alloc((size_t)NB * CAP * 4);  // ~8 MB; becomes csr in-place
    __half*   ht1  = (__half*)alloc((size_t)n * HID * 2);     // fp16 gather table
    float*    h1p  = (float*)alloc((size_t)n * HID * 4);
    __half*   ht2  = ht1;  // ht1 dead after agg1; reuse region

    hipMemsetAsync(gcursor, 0, (size_t)NB * 4, stream);

    int nch = (E + CH - 1) / CH;  // 196
    partition_kernel<<<nch, 1024, 0, stream>>>(srcv, dstv, E, gcursor, ebuf);
    localsort_kernel<<<NB, 256, 0, stream>>>(ebuf, gcursor, ns, ne, dinv, n);
    constprep_kernel<<<1, 64, 0, stream>>>(g1, be1, rm1, rv1, b1, g2, be2, rm2, rv2, b2, A1, B1, A2, B2);

    int ngb = (n + 63) / 64;      // 1563
    gemm1_kernel<<<ngb, 256, 0, stream>>>(x, W1, dinv, ht1, n);
    agg1_kernel<<<(n + 3) / 4, 256, 0, stream>>>(ht1, ns, ne, (const int*)ebuf, dinv, A1, B1, h1p, n);
    gemm2_kernel<<<ngb, 256, 0, stream>>>(h1p, W2, dinv, ht2, n);
    agg2_kernel<<<(n + 3) / 4, 256, 0, stream>>>(ht2, ns, ne, (const int*)ebuf, dinv, A2, B2, Wc, bc, out, n);
}